// Round 1
// baseline (392.028 us; speedup 1.0000x reference)
//
#include <hip/hip_runtime.h>
#include <math.h>

#define N_NODES 20000
#define N_EDGES 320000
#define DD 128
#define ND (N_NODES * DD)   // 2,560,000
#define ND4 (ND / 4)        // 640,000
#define NPG 2500            // nodes per graph (8 graphs == 8 XCDs)

// ---------------- CSR build ----------------

__global__ void count_kernel(const int* __restrict__ rows, int* __restrict__ cnt) {
    int e = blockIdx.x * blockDim.x + threadIdx.x;
    if (e < N_EDGES) atomicAdd(&cnt[rows[e]], 1);
}

__global__ __launch_bounds__(1024) void scan_kernel(const int* __restrict__ cnt,
                                                    int* __restrict__ row_start,
                                                    int* __restrict__ cursor,
                                                    float* __restrict__ redz) {
    const int t = threadIdx.x;
    // zero both red accumulator sets (2 x 14 counters, stride-16) while we're here
    if (t < 448) redz[t] = 0.0f;
    __shared__ int part[1024];
    const int CH = (N_NODES + 1023) / 1024;  // 20
    int lo = t * CH, hi = min(lo + CH, N_NODES);
    int s = 0;
    for (int i = lo; i < hi; ++i) s += cnt[i];
    part[t] = s;
    __syncthreads();
    for (int off = 1; off < 1024; off <<= 1) {
        int v = (t >= off) ? part[t - off] : 0;
        __syncthreads();
        if (t >= off) part[t] += v;
        __syncthreads();
    }
    int run = (t > 0) ? part[t - 1] : 0;
    for (int i = lo; i < hi; ++i) {
        row_start[i] = run;
        cursor[i] = run;
        run += cnt[i];
    }
    if (t == 1023) row_start[N_NODES] = part[1023];
}

__global__ void scatter_kernel(const int* __restrict__ rows, const int* __restrict__ cols,
                               const float* __restrict__ vals, int* __restrict__ cursor,
                               float2* __restrict__ epack) {
    int e = blockIdx.x * blockDim.x + threadIdx.x;
    if (e >= N_EDGES) return;
    int r = rows[e];
    int p = atomicAdd(&cursor[r], 1);
    epack[p] = make_float2(vals[e], __int_as_float(cols[e]));
}

// ---------------- f(z) = LayerNorm(K*z + A z) ----------------
// 5000 blocks x 128 threads, 2 waves/block, 2 rows/wave (one half-wave per row,
// each lane owns 4 dims -> float4 gathers). XCD swizzle: blocks with b&7==g
// land on XCD g and process only graph g's rows, so every z[col] gather hits
// that XCD's L2 (graph z-block = 1.28 MB < 4 MiB).

__global__ __launch_bounds__(128) void feval_kernel(const float* __restrict__ z,
                                                    const float* __restrict__ Kd,
                                                    const float* __restrict__ lnw,
                                                    const float* __restrict__ lnb,
                                                    const int* __restrict__ row_start,
                                                    const float2* __restrict__ epack,
                                                    float* __restrict__ out) {
    int b = blockIdx.x;
    int g = b & 7;                 // XCD id == graph id (round-robin dispatch)
    int j = b >> 3;                // 0..624 within graph
    int wv = threadIdx.x >> 6;     // wave in block: 0..1
    int lane = threadIdx.x & 63;
    int l = lane & 31;             // lane within half-wave
    int r = g * NPG + (j << 2) + (wv << 1) + (lane >> 5);
    int d0 = l << 2;               // dims d0..d0+3

    float4 zv = *(const float4*)(z + (size_t)r * DD + d0);
    float kd = Kd[r];
    float a0 = kd * zv.x, a1 = kd * zv.y, a2 = kd * zv.z, a3 = kd * zv.w;

    int e0 = row_start[r], e1 = row_start[r + 1];
    for (int base = e0; base < e1; base += 32) {
        int ew = base + l;
        float2 my_e = (ew < e1) ? epack[ew] : make_float2(0.0f, 0.0f);
        float my_val = my_e.x;
        int my_col = __float_as_int(my_e.y);
        int m = min(32, e1 - base);
        int i = 0;
        for (; i + 4 <= m; i += 4) {
            int c0 = __shfl(my_col, i, 32);
            int c1 = __shfl(my_col, i + 1, 32);
            int c2 = __shfl(my_col, i + 2, 32);
            int c3 = __shfl(my_col, i + 3, 32);
            float v0 = __shfl(my_val, i, 32);
            float v1 = __shfl(my_val, i + 1, 32);
            float v2 = __shfl(my_val, i + 2, 32);
            float v3 = __shfl(my_val, i + 3, 32);
            float4 z0 = *(const float4*)(z + (size_t)c0 * DD + d0);
            float4 z1 = *(const float4*)(z + (size_t)c1 * DD + d0);
            float4 z2 = *(const float4*)(z + (size_t)c2 * DD + d0);
            float4 z3 = *(const float4*)(z + (size_t)c3 * DD + d0);
            a0 = fmaf(v0, z0.x, a0); a1 = fmaf(v0, z0.y, a1); a2 = fmaf(v0, z0.z, a2); a3 = fmaf(v0, z0.w, a3);
            a0 = fmaf(v1, z1.x, a0); a1 = fmaf(v1, z1.y, a1); a2 = fmaf(v1, z1.z, a2); a3 = fmaf(v1, z1.w, a3);
            a0 = fmaf(v2, z2.x, a0); a1 = fmaf(v2, z2.y, a1); a2 = fmaf(v2, z2.z, a2); a3 = fmaf(v2, z2.w, a3);
            a0 = fmaf(v3, z3.x, a0); a1 = fmaf(v3, z3.y, a1); a2 = fmaf(v3, z3.z, a2); a3 = fmaf(v3, z3.w, a3);
        }
        for (; i < m; ++i) {
            int c = __shfl(my_col, i, 32);
            float v = __shfl(my_val, i, 32);
            float4 zc = *(const float4*)(z + (size_t)c * DD + d0);
            a0 = fmaf(v, zc.x, a0); a1 = fmaf(v, zc.y, a1);
            a2 = fmaf(v, zc.z, a2); a3 = fmaf(v, zc.w, a3);
        }
    }

    // half-wave (32-lane) LayerNorm stats over 128 values (4 per lane)
    float s = a0 + a1 + a2 + a3;
    float sq = a0 * a0 + a1 * a1 + a2 * a2 + a3 * a3;
#pragma unroll
    for (int off = 16; off; off >>= 1) {
        s += __shfl_xor(s, off, 64);   // offsets < 32 keep halves separate
        sq += __shfl_xor(sq, off, 64);
    }
    float mu = s * (1.0f / DD);
    float var = sq * (1.0f / DD) - mu * mu;
    float rstd = rsqrtf(var + 1e-5f);

    float4 wv4 = *(const float4*)(lnw + d0);
    float4 bv4 = *(const float4*)(lnb + d0);
    float4 ov;
    ov.x = wv4.x * (a0 - mu) * rstd + bv4.x;
    ov.y = wv4.y * (a1 - mu) * rstd + bv4.y;
    ov.z = wv4.z * (a2 - mu) * rstd + bv4.z;
    ov.w = wv4.w * (a3 - mu) * rstd + bv4.w;
    *(float4*)(out + (size_t)r * DD + d0) = ov;
}

// ---------------- Anderson reductions ----------------

struct Slots { const float* s[6]; const float* zlast; };
struct Cols5 { const float* f[5]; };

__device__ __forceinline__ float dot4(float4 a, float4 b) {
    return a.x * b.x + a.y * b.y + a.z * b.z + a.w * b.w;
}
__device__ __forceinline__ float4 sub4(float4 a, float4 b) {
    return make_float4(a.x - b.x, a.y - b.y, a.z - b.z, a.w - b.w);
}

// 2500 blocks x 256 threads, one float4 per thread (high TLP, BW-bound).
// G[c] = F[c+1]-F[c] computed on the fly from the 6 distinct history slots
// (+ zlast for the final column) -> 7 loads/elem instead of 10.
__global__ __launch_bounds__(256) void reduce_kernel(Slots sl, float* __restrict__ red) {
    int j = blockIdx.x * 256 + threadIdx.x;   // exactly ND4 threads
    float4 f[6], zl;
#pragma unroll
    for (int c = 0; c < 6; ++c) f[c] = ((const float4*)sl.s[c])[j];
    zl = ((const float4*)sl.zlast)[j];
    float4 G[5];
#pragma unroll
    for (int c = 0; c < 4; ++c) G[c] = sub4(f[c + 1], f[c]);
    G[4] = sub4(f[5], zl);
    float4 dg[4];
#pragma unroll
    for (int a = 0; a < 4; ++a) dg[a] = sub4(G[a + 1], G[a]);

    float acc[14];
    int k = 0;
#pragma unroll
    for (int a = 0; a < 4; ++a)
#pragma unroll
        for (int b = a; b < 4; ++b) { acc[k] = dot4(dg[a], dg[b]); ++k; }
#pragma unroll
    for (int a = 0; a < 4; ++a) acc[10 + a] = dot4(dg[a], G[4]);

    // wave reduce
#pragma unroll
    for (int off = 32; off; off >>= 1)
#pragma unroll
        for (int kk = 0; kk < 14; ++kk) acc[kk] += __shfl_xor(acc[kk], off, 64);

    __shared__ float sh[4][14];
    int wave = threadIdx.x >> 6, lane = threadIdx.x & 63;
    if (lane == 0)
#pragma unroll
        for (int kk = 0; kk < 14; ++kk) sh[wave][kk] = acc[kk];
    __syncthreads();
    if (threadIdx.x < 14) {
        int kk = threadIdx.x;
        atomicAdd(&red[kk * 16], sh[0][kk] + sh[1][kk] + sh[2][kk] + sh[3][kk]);
    }
}

// H = dG^T dG + 0.1 I ; solve H gamma = dG^T g_last (4x4, one thread)
__global__ void solve_kernel(const float* __restrict__ red, float* __restrict__ gam) {
    if (threadIdx.x != 0 || blockIdx.x != 0) return;
    float A[4][4], b[4];
    int k = 0;
    for (int a = 0; a < 4; ++a)
        for (int c = a; c < 4; ++c) { A[a][c] = red[k * 16]; A[c][a] = red[k * 16]; ++k; }
    for (int a = 0; a < 4; ++a) A[a][a] += 0.1f;
    for (int a = 0; a < 4; ++a) b[a] = red[(10 + a) * 16];

    for (int col = 0; col < 4; ++col) {
        int piv = col;
        float best = fabsf(A[col][col]);
        for (int rr = col + 1; rr < 4; ++rr) {
            float m = fabsf(A[rr][col]);
            if (m > best) { best = m; piv = rr; }
        }
        if (piv != col) {
            for (int c2 = 0; c2 < 4; ++c2) { float t = A[col][c2]; A[col][c2] = A[piv][c2]; A[piv][c2] = t; }
            float t = b[col]; b[col] = b[piv]; b[piv] = t;
        }
        float inv = 1.0f / A[col][col];
        for (int rr = col + 1; rr < 4; ++rr) {
            float m = A[rr][col] * inv;
            for (int c2 = col; c2 < 4; ++c2) A[rr][c2] -= m * A[col][c2];
            b[rr] -= m * b[col];
        }
    }
    float g[4];
    for (int rr = 3; rr >= 0; --rr) {
        float s = b[rr];
        for (int c2 = rr + 1; c2 < 4; ++c2) s -= A[rr][c2] * g[c2];
        g[rr] = s / A[rr][rr];
    }
    bool fin = isfinite(g[0]) && isfinite(g[1]) && isfinite(g[2]) && isfinite(g[3]);
    gam[0] = g[0]; gam[1] = g[1]; gam[2] = g[2]; gam[3] = g[3];
    gam[4] = fin ? 1.0f : 0.0f;
}

// z = f - 0.5*dF*gamma   (or f if gamma non-finite)
__global__ __launch_bounds__(256) void update_kernel(Cols5 c, const float* __restrict__ gam,
                                                     float* __restrict__ zout) {
    int j = blockIdx.x * blockDim.x + threadIdx.x;
    if (j >= ND4) return;
    float g0 = gam[0], g1 = gam[1], g2 = gam[2], g3 = gam[3], flag = gam[4];
    float4 f0 = ((const float4*)c.f[0])[j];
    float4 f1 = ((const float4*)c.f[1])[j];
    float4 f2 = ((const float4*)c.f[2])[j];
    float4 f3 = ((const float4*)c.f[3])[j];
    float4 f4 = ((const float4*)c.f[4])[j];
    float4 o;
    if (flag != 0.0f) {
        o.x = f4.x - 0.5f * ((f1.x - f0.x) * g0 + (f2.x - f1.x) * g1 + (f3.x - f2.x) * g2 + (f4.x - f3.x) * g3);
        o.y = f4.y - 0.5f * ((f1.y - f0.y) * g0 + (f2.y - f1.y) * g1 + (f3.y - f2.y) * g2 + (f4.y - f3.y) * g3);
        o.z = f4.z - 0.5f * ((f1.z - f0.z) * g0 + (f2.z - f1.z) * g1 + (f3.z - f2.z) * g2 + (f4.z - f3.z) * g3);
        o.w = f4.w - 0.5f * ((f1.w - f0.w) * g0 + (f2.w - f1.w) * g1 + (f3.w - f2.w) * g2 + (f4.w - f3.w) * g3);
    } else {
        o = f4;
    }
    ((float4*)zout)[j] = o;
}

// ---------------- host ----------------

extern "C" void kernel_launch(void* const* d_in, const int* in_sizes, int n_in,
                              void* d_out, int out_size, void* d_ws, size_t ws_size,
                              hipStream_t stream) {
    const float* x_init = (const float*)d_in[0];
    const float* Kd     = (const float*)d_in[1];
    const float* vals   = (const float*)d_in[2];
    const float* lnw    = (const float*)d_in[3];
    const float* lnb    = (const float*)d_in[4];
    const int*   rows   = (const int*)d_in[5];
    const int*   cols   = (const int*)d_in[6];
    float* out = (float*)d_out;

    char* p = (char*)d_ws;
    auto carve = [&](size_t bytes) -> void* {
        void* r = (void*)p;
        p += (bytes + 255) & ~(size_t)255;
        return r;
    };
    float*  Fh        = (float*)carve((size_t)6 * ND * 4);   // rolling f_t history, slot t%6
    float*  red       = (float*)carve(4096);                 // 2 sets x 14 counters, stride-16
    float*  gam       = (float*)carve(256);                  // gamma[0..3] + finite flag
    int*    row_start = (int*)carve((N_NODES + 1) * 4);
    int*    cursor    = (int*)carve(N_NODES * 4);
    int*    cnt       = (int*)carve(N_NODES * 4);
    float2* epack     = (float2*)carve((size_t)N_EDGES * 8);
    float*  zA        = out;  // d_out doubles as storage for Anderson z7

    // CSR build (once per launch); scan also zeros both red sets
    hipMemsetAsync(cnt, 0, N_NODES * 4, stream);
    count_kernel<<<(N_EDGES + 255) / 256, 256, 0, stream>>>(rows, cnt);
    scan_kernel<<<1, 1024, 0, stream>>>(cnt, row_start, cursor, red);
    scatter_kernel<<<(N_EDGES + 255) / 256, 256, 0, stream>>>(rows, cols, vals, cursor, epack);

    auto Fslot = [&](int t) -> float* { return Fh + (size_t)(t % 6) * ND; };

    for (int t = 0; t < 8; ++t) {
        const float* zsrc = (t == 0) ? x_init : (t <= 6 ? Fslot(t - 1) : zA);
        feval_kernel<<<5000, 128, 0, stream>>>(zsrc, Kd, lnw, lnb, row_start, epack, Fslot(t));

        if (t >= 6) {
            float* redt = red + (t - 6) * 224;   // separate pre-zeroed set per step
            Slots sl;
            for (int i = 0; i < 6; ++i) sl.s[i] = Fslot(t - 5 + i);
            sl.zlast = (t == 7) ? (const float*)zA : (const float*)Fslot(t - 1);
            reduce_kernel<<<2500, 256, 0, stream>>>(sl, redt);
            solve_kernel<<<1, 64, 0, stream>>>(redt, gam);

            Cols5 uc;
            for (int c2 = 0; c2 < 5; ++c2) uc.f[c2] = Fslot(t - 4 + c2);
            float* zdst = (t == 6) ? zA : out;
            update_kernel<<<(ND4 + 255) / 256, 256, 0, stream>>>(uc, gam, zdst);
        }
    }
}

// Round 2
// 306.810 us; speedup vs baseline: 1.2778x; 1.2778x over previous
//
#include <hip/hip_runtime.h>
#include <math.h>

#define N_NODES 20000
#define N_EDGES 320000
#define DD 128
#define ND (N_NODES * DD)   // 2,560,000
#define ND4 (ND / 4)        // 640,000
#define NPG 2500            // nodes per graph (8 graphs == 8 XCDs)

// ---------------- CSR build ----------------

__global__ void count_kernel(const int* __restrict__ rows, int* __restrict__ cnt) {
    int e = blockIdx.x * blockDim.x + threadIdx.x;
    if (e < N_EDGES) atomicAdd(&cnt[rows[e]], 1);
}

__global__ __launch_bounds__(1024) void scan_kernel(const int* __restrict__ cnt,
                                                    int* __restrict__ row_start,
                                                    int* __restrict__ cursor,
                                                    float* __restrict__ redz) {
    const int t = threadIdx.x;
    // zero both red accumulator sets (2 x 14 counters, stride-16) while we're here
    if (t < 448) redz[t] = 0.0f;
    __shared__ int part[1024];
    const int CH = (N_NODES + 1023) / 1024;  // 20
    int lo = t * CH, hi = min(lo + CH, N_NODES);
    int s = 0;
    for (int i = lo; i < hi; ++i) s += cnt[i];
    part[t] = s;
    __syncthreads();
    for (int off = 1; off < 1024; off <<= 1) {
        int v = (t >= off) ? part[t - off] : 0;
        __syncthreads();
        if (t >= off) part[t] += v;
        __syncthreads();
    }
    int run = (t > 0) ? part[t - 1] : 0;
    for (int i = lo; i < hi; ++i) {
        row_start[i] = run;
        cursor[i] = run;
        run += cnt[i];
    }
    if (t == 1023) row_start[N_NODES] = part[1023];
}

__global__ void scatter_kernel(const int* __restrict__ rows, const int* __restrict__ cols,
                               const float* __restrict__ vals, int* __restrict__ cursor,
                               float2* __restrict__ epack) {
    int e = blockIdx.x * blockDim.x + threadIdx.x;
    if (e >= N_EDGES) return;
    int r = rows[e];
    int p = atomicAdd(&cursor[r], 1);
    epack[p] = make_float2(vals[e], __int_as_float(cols[e]));
}

// ---------------- f(z) = LayerNorm(K*z + A z) ----------------
// 5000 blocks x 128 threads, 2 waves/block, 2 rows/wave (one half-wave per row,
// each lane owns 4 dims -> float4 gathers). XCD swizzle: blocks with b&7==g
// land on XCD g and process only graph g's rows, so every z[col] gather hits
// that XCD's L2 (graph z-block = 1.28 MB < 4 MiB).

__global__ __launch_bounds__(128) void feval_kernel(const float* __restrict__ z,
                                                    const float* __restrict__ Kd,
                                                    const float* __restrict__ lnw,
                                                    const float* __restrict__ lnb,
                                                    const int* __restrict__ row_start,
                                                    const float2* __restrict__ epack,
                                                    float* __restrict__ out) {
    int b = blockIdx.x;
    int g = b & 7;                 // XCD id == graph id (round-robin dispatch)
    int j = b >> 3;                // 0..624 within graph
    int wv = threadIdx.x >> 6;     // wave in block: 0..1
    int lane = threadIdx.x & 63;
    int l = lane & 31;             // lane within half-wave
    int r = g * NPG + (j << 2) + (wv << 1) + (lane >> 5);
    int d0 = l << 2;               // dims d0..d0+3

    float4 zv = *(const float4*)(z + (size_t)r * DD + d0);
    float kd = Kd[r];
    float a0 = kd * zv.x, a1 = kd * zv.y, a2 = kd * zv.z, a3 = kd * zv.w;

    int e0 = row_start[r], e1 = row_start[r + 1];
    for (int base = e0; base < e1; base += 32) {
        int ew = base + l;
        float2 my_e = (ew < e1) ? epack[ew] : make_float2(0.0f, 0.0f);
        float my_val = my_e.x;
        int my_col = __float_as_int(my_e.y);
        int m = min(32, e1 - base);
        int i = 0;
        for (; i + 4 <= m; i += 4) {
            int c0 = __shfl(my_col, i, 32);
            int c1 = __shfl(my_col, i + 1, 32);
            int c2 = __shfl(my_col, i + 2, 32);
            int c3 = __shfl(my_col, i + 3, 32);
            float v0 = __shfl(my_val, i, 32);
            float v1 = __shfl(my_val, i + 1, 32);
            float v2 = __shfl(my_val, i + 2, 32);
            float v3 = __shfl(my_val, i + 3, 32);
            float4 z0 = *(const float4*)(z + (size_t)c0 * DD + d0);
            float4 z1 = *(const float4*)(z + (size_t)c1 * DD + d0);
            float4 z2 = *(const float4*)(z + (size_t)c2 * DD + d0);
            float4 z3 = *(const float4*)(z + (size_t)c3 * DD + d0);
            a0 = fmaf(v0, z0.x, a0); a1 = fmaf(v0, z0.y, a1); a2 = fmaf(v0, z0.z, a2); a3 = fmaf(v0, z0.w, a3);
            a0 = fmaf(v1, z1.x, a0); a1 = fmaf(v1, z1.y, a1); a2 = fmaf(v1, z1.z, a2); a3 = fmaf(v1, z1.w, a3);
            a0 = fmaf(v2, z2.x, a0); a1 = fmaf(v2, z2.y, a1); a2 = fmaf(v2, z2.z, a2); a3 = fmaf(v2, z2.w, a3);
            a0 = fmaf(v3, z3.x, a0); a1 = fmaf(v3, z3.y, a1); a2 = fmaf(v3, z3.z, a2); a3 = fmaf(v3, z3.w, a3);
        }
        for (; i < m; ++i) {
            int c = __shfl(my_col, i, 32);
            float v = __shfl(my_val, i, 32);
            float4 zc = *(const float4*)(z + (size_t)c * DD + d0);
            a0 = fmaf(v, zc.x, a0); a1 = fmaf(v, zc.y, a1);
            a2 = fmaf(v, zc.z, a2); a3 = fmaf(v, zc.w, a3);
        }
    }

    // half-wave (32-lane) LayerNorm stats over 128 values (4 per lane)
    float s = a0 + a1 + a2 + a3;
    float sq = a0 * a0 + a1 * a1 + a2 * a2 + a3 * a3;
#pragma unroll
    for (int off = 16; off; off >>= 1) {
        s += __shfl_xor(s, off, 64);   // offsets < 32 keep halves separate
        sq += __shfl_xor(sq, off, 64);
    }
    float mu = s * (1.0f / DD);
    float var = sq * (1.0f / DD) - mu * mu;
    float rstd = rsqrtf(var + 1e-5f);

    float4 wv4 = *(const float4*)(lnw + d0);
    float4 bv4 = *(const float4*)(lnb + d0);
    float4 ov;
    ov.x = wv4.x * (a0 - mu) * rstd + bv4.x;
    ov.y = wv4.y * (a1 - mu) * rstd + bv4.y;
    ov.z = wv4.z * (a2 - mu) * rstd + bv4.z;
    ov.w = wv4.w * (a3 - mu) * rstd + bv4.w;
    *(float4*)(out + (size_t)r * DD + d0) = ov;
}

// ---------------- Anderson reductions ----------------

struct Slots { const float* s[6]; const float* zlast; };
struct Cols5 { const float* f[5]; };

__device__ __forceinline__ float dot4(float4 a, float4 b) {
    return a.x * b.x + a.y * b.y + a.z * b.z + a.w * b.w;
}
__device__ __forceinline__ float4 sub4(float4 a, float4 b) {
    return make_float4(a.x - b.x, a.y - b.y, a.z - b.z, a.w - b.w);
}

// 625 blocks x 256 threads; each thread owns 4 j's (2 phases x 2 elements).
// 7 streams (6 history slots + zlast), G computed on the fly -> 7 loads/elem,
// 14 float4 loads in flight per phase; the 84-shuffle reduction epilogue is
// amortized over 4 elements (the round-1 regression was paying it per element).
#define RED_T 160000
__global__ __launch_bounds__(256) void reduce_kernel(Slots sl, float* __restrict__ red) {
    int tid = blockIdx.x * 256 + threadIdx.x;
    float acc[14];
#pragma unroll
    for (int k = 0; k < 14; ++k) acc[k] = 0.f;

#pragma unroll
    for (int ph = 0; ph < 2; ++ph) {
        int ja = tid + (2 * ph) * RED_T;
        int jb = ja + RED_T;
        float4 fa[6], fb[6];
#pragma unroll
        for (int c = 0; c < 6; ++c) {
            fa[c] = ((const float4*)sl.s[c])[ja];
            fb[c] = ((const float4*)sl.s[c])[jb];
        }
        float4 zla = ((const float4*)sl.zlast)[ja];
        float4 zlb = ((const float4*)sl.zlast)[jb];
        float4 Ga[5], Gb[5];
#pragma unroll
        for (int c = 0; c < 4; ++c) { Ga[c] = sub4(fa[c + 1], fa[c]); Gb[c] = sub4(fb[c + 1], fb[c]); }
        Ga[4] = sub4(fa[5], zla);
        Gb[4] = sub4(fb[5], zlb);
        float4 dga[4], dgb[4];
#pragma unroll
        for (int a = 0; a < 4; ++a) { dga[a] = sub4(Ga[a + 1], Ga[a]); dgb[a] = sub4(Gb[a + 1], Gb[a]); }
        int k = 0;
#pragma unroll
        for (int a = 0; a < 4; ++a)
#pragma unroll
            for (int b = a; b < 4; ++b) { acc[k] += dot4(dga[a], dga[b]) + dot4(dgb[a], dgb[b]); ++k; }
#pragma unroll
        for (int a = 0; a < 4; ++a) acc[10 + a] += dot4(dga[a], Ga[4]) + dot4(dgb[a], Gb[4]);
    }

    // wave reduce (once per thread, amortized over 4 elements)
#pragma unroll
    for (int off = 32; off; off >>= 1)
#pragma unroll
        for (int kk = 0; kk < 14; ++kk) acc[kk] += __shfl_xor(acc[kk], off, 64);

    __shared__ float sh[4][14];
    int wave = threadIdx.x >> 6, lane = threadIdx.x & 63;
    if (lane == 0)
#pragma unroll
        for (int kk = 0; kk < 14; ++kk) sh[wave][kk] = acc[kk];
    __syncthreads();
    if (threadIdx.x < 14) {
        int kk = threadIdx.x;
        atomicAdd(&red[kk * 16], sh[0][kk] + sh[1][kk] + sh[2][kk] + sh[3][kk]);
    }
}

// H = dG^T dG + 0.1 I ; solve H gamma = dG^T g_last (4x4, one thread)
__global__ void solve_kernel(const float* __restrict__ red, float* __restrict__ gam) {
    if (threadIdx.x != 0 || blockIdx.x != 0) return;
    float A[4][4], b[4];
    int k = 0;
    for (int a = 0; a < 4; ++a)
        for (int c = a; c < 4; ++c) { A[a][c] = red[k * 16]; A[c][a] = red[k * 16]; ++k; }
    for (int a = 0; a < 4; ++a) A[a][a] += 0.1f;
    for (int a = 0; a < 4; ++a) b[a] = red[(10 + a) * 16];

    for (int col = 0; col < 4; ++col) {
        int piv = col;
        float best = fabsf(A[col][col]);
        for (int rr = col + 1; rr < 4; ++rr) {
            float m = fabsf(A[rr][col]);
            if (m > best) { best = m; piv = rr; }
        }
        if (piv != col) {
            for (int c2 = 0; c2 < 4; ++c2) { float t = A[col][c2]; A[col][c2] = A[piv][c2]; A[piv][c2] = t; }
            float t = b[col]; b[col] = b[piv]; b[piv] = t;
        }
        float inv = 1.0f / A[col][col];
        for (int rr = col + 1; rr < 4; ++rr) {
            float m = A[rr][col] * inv;
            for (int c2 = col; c2 < 4; ++c2) A[rr][c2] -= m * A[col][c2];
            b[rr] -= m * b[col];
        }
    }
    float g[4];
    for (int rr = 3; rr >= 0; --rr) {
        float s = b[rr];
        for (int c2 = rr + 1; c2 < 4; ++c2) s -= A[rr][c2] * g[c2];
        g[rr] = s / A[rr][rr];
    }
    bool fin = isfinite(g[0]) && isfinite(g[1]) && isfinite(g[2]) && isfinite(g[3]);
    gam[0] = g[0]; gam[1] = g[1]; gam[2] = g[2]; gam[3] = g[3];
    gam[4] = fin ? 1.0f : 0.0f;
}

// z = f - 0.5*dF*gamma   (or f if gamma non-finite)
__global__ __launch_bounds__(256) void update_kernel(Cols5 c, const float* __restrict__ gam,
                                                     float* __restrict__ zout) {
    int j = blockIdx.x * blockDim.x + threadIdx.x;
    if (j >= ND4) return;
    float g0 = gam[0], g1 = gam[1], g2 = gam[2], g3 = gam[3], flag = gam[4];
    float4 f0 = ((const float4*)c.f[0])[j];
    float4 f1 = ((const float4*)c.f[1])[j];
    float4 f2 = ((const float4*)c.f[2])[j];
    float4 f3 = ((const float4*)c.f[3])[j];
    float4 f4 = ((const float4*)c.f[4])[j];
    float4 o;
    if (flag != 0.0f) {
        o.x = f4.x - 0.5f * ((f1.x - f0.x) * g0 + (f2.x - f1.x) * g1 + (f3.x - f2.x) * g2 + (f4.x - f3.x) * g3);
        o.y = f4.y - 0.5f * ((f1.y - f0.y) * g0 + (f2.y - f1.y) * g1 + (f3.y - f2.y) * g2 + (f4.y - f3.y) * g3);
        o.z = f4.z - 0.5f * ((f1.z - f0.z) * g0 + (f2.z - f1.z) * g1 + (f3.z - f2.z) * g2 + (f4.z - f3.z) * g3);
        o.w = f4.w - 0.5f * ((f1.w - f0.w) * g0 + (f2.w - f1.w) * g1 + (f3.w - f2.w) * g2 + (f4.w - f3.w) * g3);
    } else {
        o = f4;
    }
    ((float4*)zout)[j] = o;
}

// ---------------- host ----------------

extern "C" void kernel_launch(void* const* d_in, const int* in_sizes, int n_in,
                              void* d_out, int out_size, void* d_ws, size_t ws_size,
                              hipStream_t stream) {
    const float* x_init = (const float*)d_in[0];
    const float* Kd     = (const float*)d_in[1];
    const float* vals   = (const float*)d_in[2];
    const float* lnw    = (const float*)d_in[3];
    const float* lnb    = (const float*)d_in[4];
    const int*   rows   = (const int*)d_in[5];
    const int*   cols   = (const int*)d_in[6];
    float* out = (float*)d_out;

    char* p = (char*)d_ws;
    auto carve = [&](size_t bytes) -> void* {
        void* r = (void*)p;
        p += (bytes + 255) & ~(size_t)255;
        return r;
    };
    float*  Fh        = (float*)carve((size_t)6 * ND * 4);   // rolling f_t history, slot t%6
    float*  red       = (float*)carve(4096);                 // 2 sets x 14 counters, stride-16
    float*  gam       = (float*)carve(256);                  // gamma[0..3] + finite flag
    int*    row_start = (int*)carve((N_NODES + 1) * 4);
    int*    cursor    = (int*)carve(N_NODES * 4);
    int*    cnt       = (int*)carve(N_NODES * 4);
    float2* epack     = (float2*)carve((size_t)N_EDGES * 8);
    float*  zA        = out;  // d_out doubles as storage for Anderson z7

    // CSR build (once per launch); scan also zeros both red sets
    hipMemsetAsync(cnt, 0, N_NODES * 4, stream);
    count_kernel<<<(N_EDGES + 255) / 256, 256, 0, stream>>>(rows, cnt);
    scan_kernel<<<1, 1024, 0, stream>>>(cnt, row_start, cursor, red);
    scatter_kernel<<<(N_EDGES + 255) / 256, 256, 0, stream>>>(rows, cols, vals, cursor, epack);

    auto Fslot = [&](int t) -> float* { return Fh + (size_t)(t % 6) * ND; };

    for (int t = 0; t < 8; ++t) {
        const float* zsrc = (t == 0) ? x_init : (t <= 6 ? Fslot(t - 1) : zA);
        feval_kernel<<<5000, 128, 0, stream>>>(zsrc, Kd, lnw, lnb, row_start, epack, Fslot(t));

        if (t >= 6) {
            float* redt = red + (t - 6) * 224;   // separate pre-zeroed set per step
            Slots sl;
            for (int i = 0; i < 6; ++i) sl.s[i] = Fslot(t - 5 + i);
            sl.zlast = (t == 7) ? (const float*)zA : (const float*)Fslot(t - 1);
            reduce_kernel<<<625, 256, 0, stream>>>(sl, redt);
            solve_kernel<<<1, 64, 0, stream>>>(redt, gam);

            Cols5 uc;
            for (int c2 = 0; c2 < 5; ++c2) uc.f[c2] = Fslot(t - 4 + c2);
            float* zdst = (t == 6) ? zA : out;
            update_kernel<<<(ND4 + 255) / 256, 256, 0, stream>>>(uc, gam, zdst);
        }
    }
}

// Round 3
// 306.234 us; speedup vs baseline: 1.2802x; 1.0019x over previous
//
#include <hip/hip_runtime.h>
#include <math.h>

#define N_NODES 20000
#define N_EDGES 320000
#define DD 128
#define ND (N_NODES * DD)   // 2,560,000
#define ND4 (ND / 4)        // 640,000
#define NPG 2500            // nodes per graph (8 graphs == 8 XCDs)

// ---------------- CSR build ----------------

__global__ void count_kernel(const int* __restrict__ rows, int* __restrict__ cnt) {
    int e = blockIdx.x * blockDim.x + threadIdx.x;
    if (e < N_EDGES) atomicAdd(&cnt[rows[e]], 1);
}

__global__ __launch_bounds__(1024) void scan_kernel(const int* __restrict__ cnt,
                                                    int* __restrict__ row_start,
                                                    int* __restrict__ cursor,
                                                    float* __restrict__ redz) {
    const int t = threadIdx.x;
    // zero both red accumulator sets (2 x 14 counters, stride-16) while we're here
    if (t < 448) redz[t] = 0.0f;
    __shared__ int part[1024];
    const int CH = (N_NODES + 1023) / 1024;  // 20
    int lo = t * CH, hi = min(lo + CH, N_NODES);
    int s = 0;
    for (int i = lo; i < hi; ++i) s += cnt[i];
    part[t] = s;
    __syncthreads();
    for (int off = 1; off < 1024; off <<= 1) {
        int v = (t >= off) ? part[t - off] : 0;
        __syncthreads();
        if (t >= off) part[t] += v;
        __syncthreads();
    }
    int run = (t > 0) ? part[t - 1] : 0;
    for (int i = lo; i < hi; ++i) {
        row_start[i] = run;
        cursor[i] = run;
        run += cnt[i];
    }
    if (t == 1023) row_start[N_NODES] = part[1023];
}

__global__ void scatter_kernel(const int* __restrict__ rows, const int* __restrict__ cols,
                               const float* __restrict__ vals, int* __restrict__ cursor,
                               float2* __restrict__ epack) {
    int e = blockIdx.x * blockDim.x + threadIdx.x;
    if (e >= N_EDGES) return;
    int r = rows[e];
    int p = atomicAdd(&cursor[r], 1);
    epack[p] = make_float2(vals[e], __int_as_float(cols[e]));
}

// ---------------- f(z) = LayerNorm(K*z + A z) ----------------
// 5000 blocks x 128 threads, 2 waves/block, 2 rows/wave (one half-wave per row,
// each lane owns 4 dims -> float4 gathers). XCD swizzle: blocks with b&7==g
// land on XCD g and process only graph g's rows, so every z[col] gather hits
// that XCD's L2 (graph z-block = 1.28 MB < 4 MiB).
// 8-deep edge unroll: 8 float4 gathers in flight per half-wave (latency-bound fix).

__global__ __launch_bounds__(128) void feval_kernel(const float* __restrict__ z,
                                                    const float* __restrict__ Kd,
                                                    const float* __restrict__ lnw,
                                                    const float* __restrict__ lnb,
                                                    const int* __restrict__ row_start,
                                                    const float2* __restrict__ epack,
                                                    float* __restrict__ out) {
    int b = blockIdx.x;
    int g = b & 7;                 // XCD id == graph id (round-robin dispatch)
    int j = b >> 3;                // 0..624 within graph
    int wv = threadIdx.x >> 6;     // wave in block: 0..1
    int lane = threadIdx.x & 63;
    int l = lane & 31;             // lane within half-wave
    int r = g * NPG + (j << 2) + (wv << 1) + (lane >> 5);
    int d0 = l << 2;               // dims d0..d0+3

    int e0 = row_start[r], e1 = row_start[r + 1];

    float4 zv = *(const float4*)(z + (size_t)r * DD + d0);
    float kd = Kd[r];
    float a0 = kd * zv.x, a1 = kd * zv.y, a2 = kd * zv.z, a3 = kd * zv.w;

    for (int base = e0; base < e1; base += 32) {
        int ew = base + l;
        float2 my_e = (ew < e1) ? epack[ew] : make_float2(0.0f, 0.0f);
        float my_val = my_e.x;
        int my_col = __float_as_int(my_e.y);
        int m = min(32, e1 - base);
        int i = 0;
        for (; i + 8 <= m; i += 8) {
            int c[8]; float v[8];
#pragma unroll
            for (int u = 0; u < 8; ++u) {
                c[u] = __shfl(my_col, i + u, 32);
                v[u] = __shfl(my_val, i + u, 32);
            }
            float4 zr[8];
#pragma unroll
            for (int u = 0; u < 8; ++u) zr[u] = *(const float4*)(z + (size_t)c[u] * DD + d0);
#pragma unroll
            for (int u = 0; u < 8; ++u) {
                a0 = fmaf(v[u], zr[u].x, a0); a1 = fmaf(v[u], zr[u].y, a1);
                a2 = fmaf(v[u], zr[u].z, a2); a3 = fmaf(v[u], zr[u].w, a3);
            }
        }
        for (; i < m; ++i) {
            int c = __shfl(my_col, i, 32);
            float v = __shfl(my_val, i, 32);
            float4 zc = *(const float4*)(z + (size_t)c * DD + d0);
            a0 = fmaf(v, zc.x, a0); a1 = fmaf(v, zc.y, a1);
            a2 = fmaf(v, zc.z, a2); a3 = fmaf(v, zc.w, a3);
        }
    }

    // half-wave (32-lane) LayerNorm stats over 128 values (4 per lane)
    float s = a0 + a1 + a2 + a3;
    float sq = a0 * a0 + a1 * a1 + a2 * a2 + a3 * a3;
#pragma unroll
    for (int off = 16; off; off >>= 1) {
        s += __shfl_xor(s, off, 64);   // offsets < 32 keep halves separate
        sq += __shfl_xor(sq, off, 64);
    }
    float mu = s * (1.0f / DD);
    float var = sq * (1.0f / DD) - mu * mu;
    float rstd = rsqrtf(var + 1e-5f);

    float4 wv4 = *(const float4*)(lnw + d0);
    float4 bv4 = *(const float4*)(lnb + d0);
    float4 ov;
    ov.x = wv4.x * (a0 - mu) * rstd + bv4.x;
    ov.y = wv4.y * (a1 - mu) * rstd + bv4.y;
    ov.z = wv4.z * (a2 - mu) * rstd + bv4.z;
    ov.w = wv4.w * (a3 - mu) * rstd + bv4.w;
    *(float4*)(out + (size_t)r * DD + d0) = ov;
}

// ---------------- Anderson reductions ----------------

struct Slots { const float* s[6]; const float* zlast; };
struct Cols5 { const float* f[5]; };

__device__ __forceinline__ float dot4(float4 a, float4 b) {
    return a.x * b.x + a.y * b.y + a.z * b.z + a.w * b.w;
}
__device__ __forceinline__ float4 sub4(float4 a, float4 b) {
    return make_float4(a.x - b.x, a.y - b.y, a.z - b.z, a.w - b.w);
}

// 625 blocks x 256 threads; each thread owns 4 j's (2 phases x 2 elements).
// 7 streams (6 history slots + zlast), G computed on the fly -> 7 loads/elem,
// 14 float4 loads in flight per phase; the 84-shuffle reduction epilogue is
// amortized over 4 elements.
#define RED_T 160000
__global__ __launch_bounds__(256) void reduce_kernel(Slots sl, float* __restrict__ red) {
    int tid = blockIdx.x * 256 + threadIdx.x;
    float acc[14];
#pragma unroll
    for (int k = 0; k < 14; ++k) acc[k] = 0.f;

#pragma unroll
    for (int ph = 0; ph < 2; ++ph) {
        int ja = tid + (2 * ph) * RED_T;
        int jb = ja + RED_T;
        float4 fa[6], fb[6];
#pragma unroll
        for (int c = 0; c < 6; ++c) {
            fa[c] = ((const float4*)sl.s[c])[ja];
            fb[c] = ((const float4*)sl.s[c])[jb];
        }
        float4 zla = ((const float4*)sl.zlast)[ja];
        float4 zlb = ((const float4*)sl.zlast)[jb];
        float4 Ga[5], Gb[5];
#pragma unroll
        for (int c = 0; c < 4; ++c) { Ga[c] = sub4(fa[c + 1], fa[c]); Gb[c] = sub4(fb[c + 1], fb[c]); }
        Ga[4] = sub4(fa[5], zla);
        Gb[4] = sub4(fb[5], zlb);
        float4 dga[4], dgb[4];
#pragma unroll
        for (int a = 0; a < 4; ++a) { dga[a] = sub4(Ga[a + 1], Ga[a]); dgb[a] = sub4(Gb[a + 1], Gb[a]); }
        int k = 0;
#pragma unroll
        for (int a = 0; a < 4; ++a)
#pragma unroll
            for (int b = a; b < 4; ++b) { acc[k] += dot4(dga[a], dga[b]) + dot4(dgb[a], dgb[b]); ++k; }
#pragma unroll
        for (int a = 0; a < 4; ++a) acc[10 + a] += dot4(dga[a], Ga[4]) + dot4(dgb[a], Gb[4]);
    }

    // wave reduce (once per thread, amortized over 4 elements)
#pragma unroll
    for (int off = 32; off; off >>= 1)
#pragma unroll
        for (int kk = 0; kk < 14; ++kk) acc[kk] += __shfl_xor(acc[kk], off, 64);

    __shared__ float sh[4][14];
    int wave = threadIdx.x >> 6, lane = threadIdx.x & 63;
    if (lane == 0)
#pragma unroll
        for (int kk = 0; kk < 14; ++kk) sh[wave][kk] = acc[kk];
    __syncthreads();
    if (threadIdx.x < 14) {
        int kk = threadIdx.x;
        atomicAdd(&red[kk * 16], sh[0][kk] + sh[1][kk] + sh[2][kk] + sh[3][kk]);
    }
}

// H = dG^T dG + 0.1 I is SPD (lambda_min >= 0.1) -> unpivoted elimination is
// stable and fully unrollable (static indices only, stays in registers).
__device__ __forceinline__ float solve_gamma(const float* __restrict__ red, float* g) {
    float A[4][4], b[4];
    int k = 0;
#pragma unroll
    for (int a = 0; a < 4; ++a)
#pragma unroll
        for (int c = 0; c < 4; ++c) A[a][c] = 0.f;
#pragma unroll
    for (int a = 0; a < 4; ++a)
#pragma unroll
        for (int c = a; c < 4; ++c) { float h = red[k * 16]; A[a][c] = h; A[c][a] = h; ++k; }
#pragma unroll
    for (int a = 0; a < 4; ++a) A[a][a] += 0.1f;
#pragma unroll
    for (int a = 0; a < 4; ++a) b[a] = red[(10 + a) * 16];

#pragma unroll
    for (int col = 0; col < 4; ++col) {
        float inv = 1.0f / A[col][col];
#pragma unroll
        for (int rr = 0; rr < 4; ++rr) {
            if (rr > col) {
                float m = A[rr][col] * inv;
#pragma unroll
                for (int c2 = 0; c2 < 4; ++c2)
                    if (c2 >= col) A[rr][c2] -= m * A[col][c2];
                b[rr] -= m * b[col];
            }
        }
    }
#pragma unroll
    for (int rr = 3; rr >= 0; --rr) {
        float s = b[rr];
#pragma unroll
        for (int c2 = 0; c2 < 4; ++c2)
            if (c2 > rr) s -= A[rr][c2] * g[c2];
        g[rr] = s / A[rr][rr];
    }
    bool fin = isfinite(g[0]) && isfinite(g[1]) && isfinite(g[2]) && isfinite(g[3]);
    return fin ? 1.0f : 0.0f;
}

// z = f - 0.5*dF*gamma (or f if gamma non-finite). Solve fused in (uniform,
// ~100 scalar flops per thread, no extra dispatch).
__global__ __launch_bounds__(256) void update_kernel(Cols5 c, const float* __restrict__ red,
                                                     float* __restrict__ zout) {
    int j = blockIdx.x * blockDim.x + threadIdx.x;
    if (j >= ND4) return;
    float g[4];
    float flag = solve_gamma(red, g);
    float g0 = g[0], g1 = g[1], g2 = g[2], g3 = g[3];
    float4 f0 = ((const float4*)c.f[0])[j];
    float4 f1 = ((const float4*)c.f[1])[j];
    float4 f2 = ((const float4*)c.f[2])[j];
    float4 f3 = ((const float4*)c.f[3])[j];
    float4 f4 = ((const float4*)c.f[4])[j];
    float4 o;
    if (flag != 0.0f) {
        o.x = f4.x - 0.5f * ((f1.x - f0.x) * g0 + (f2.x - f1.x) * g1 + (f3.x - f2.x) * g2 + (f4.x - f3.x) * g3);
        o.y = f4.y - 0.5f * ((f1.y - f0.y) * g0 + (f2.y - f1.y) * g1 + (f3.y - f2.y) * g2 + (f4.y - f3.y) * g3);
        o.z = f4.z - 0.5f * ((f1.z - f0.z) * g0 + (f2.z - f1.z) * g1 + (f3.z - f2.z) * g2 + (f4.z - f3.z) * g3);
        o.w = f4.w - 0.5f * ((f1.w - f0.w) * g0 + (f2.w - f1.w) * g1 + (f3.w - f2.w) * g2 + (f4.w - f3.w) * g3);
    } else {
        o = f4;
    }
    ((float4*)zout)[j] = o;
}

// ---------------- host ----------------

extern "C" void kernel_launch(void* const* d_in, const int* in_sizes, int n_in,
                              void* d_out, int out_size, void* d_ws, size_t ws_size,
                              hipStream_t stream) {
    const float* x_init = (const float*)d_in[0];
    const float* Kd     = (const float*)d_in[1];
    const float* vals   = (const float*)d_in[2];
    const float* lnw    = (const float*)d_in[3];
    const float* lnb    = (const float*)d_in[4];
    const int*   rows   = (const int*)d_in[5];
    const int*   cols   = (const int*)d_in[6];
    float* out = (float*)d_out;

    char* p = (char*)d_ws;
    auto carve = [&](size_t bytes) -> void* {
        void* r = (void*)p;
        p += (bytes + 255) & ~(size_t)255;
        return r;
    };
    float*  Fh        = (float*)carve((size_t)6 * ND * 4);   // rolling f_t history, slot t%6
    float*  red       = (float*)carve(4096);                 // 2 sets x 14 counters, stride-16
    int*    row_start = (int*)carve((N_NODES + 1) * 4);
    int*    cursor    = (int*)carve(N_NODES * 4);
    int*    cnt       = (int*)carve(N_NODES * 4);
    float2* epack     = (float2*)carve((size_t)N_EDGES * 8);
    float*  zA        = out;  // d_out doubles as storage for Anderson z7

    // CSR build (once per launch); scan also zeros both red sets
    hipMemsetAsync(cnt, 0, N_NODES * 4, stream);
    count_kernel<<<(N_EDGES + 255) / 256, 256, 0, stream>>>(rows, cnt);
    scan_kernel<<<1, 1024, 0, stream>>>(cnt, row_start, cursor, red);
    scatter_kernel<<<(N_EDGES + 255) / 256, 256, 0, stream>>>(rows, cols, vals, cursor, epack);

    auto Fslot = [&](int t) -> float* { return Fh + (size_t)(t % 6) * ND; };

    for (int t = 0; t < 8; ++t) {
        const float* zsrc = (t == 0) ? x_init : (t <= 6 ? Fslot(t - 1) : zA);
        feval_kernel<<<5000, 128, 0, stream>>>(zsrc, Kd, lnw, lnb, row_start, epack, Fslot(t));

        if (t >= 6) {
            float* redt = red + (t - 6) * 224;   // separate pre-zeroed set per step
            Slots sl;
            for (int i = 0; i < 6; ++i) sl.s[i] = Fslot(t - 5 + i);
            sl.zlast = (t == 7) ? (const float*)zA : (const float*)Fslot(t - 1);
            reduce_kernel<<<625, 256, 0, stream>>>(sl, redt);

            Cols5 uc;
            for (int c2 = 0; c2 < 5; ++c2) uc.f[c2] = Fslot(t - 4 + c2);
            float* zdst = (t == 6) ? zA : out;
            update_kernel<<<(ND4 + 255) / 256, 256, 0, stream>>>(uc, redt, zdst);
        }
    }
}